// Round 1
// baseline (628.589 us; speedup 1.0000x reference)
//
#include <hip/hip_runtime.h>
#include <math.h>

#define DT_STEP 0.1f

static __device__ __forceinline__ float lrelu(float z) { return z >= 0.0f ? z : 0.1f * z; }

static __device__ __forceinline__ void mm3(const float* A, const float* B, float* C) {
#pragma unroll
    for (int i = 0; i < 3; ++i) {
#pragma unroll
        for (int j = 0; j < 3; ++j) {
            C[i * 3 + j] = A[i * 3 + 0] * B[0 * 3 + j] + A[i * 3 + 1] * B[1 * 3 + j] + A[i * 3 + 2] * B[2 * 3 + j];
        }
    }
}

static __device__ __forceinline__ void mv3(const float* A, const float* x, float* y) {
#pragma unroll
    for (int i = 0; i < 3; ++i)
        y[i] = A[i * 3 + 0] * x[0] + A[i * 3 + 1] * x[1] + A[i * 3 + 2] * x[2];
}

// y = A^T x
static __device__ __forceinline__ void mtv3(const float* A, const float* x, float* y) {
#pragma unroll
    for (int i = 0; i < 3; ++i)
        y[i] = A[0 * 3 + i] * x[0] + A[1 * 3 + i] * x[1] + A[2 * 3 + i] * x[2];
}

static __device__ __forceinline__ void cross3(const float* p, const float* u, float* y) {
    y[0] = p[1] * u[2] - p[2] * u[1];
    y[1] = p[2] * u[0] - p[0] * u[2];
    y[2] = p[0] * u[1] - p[1] * u[0];
}

__global__ __launch_bounds__(256)
void auv_step_kernel(const float* __restrict__ s, const float* __restrict__ a,
                     const float* __restrict__ h0, const float* __restrict__ W_ih,
                     const float* __restrict__ W_hh, const float* __restrict__ W1,
                     const float* __restrict__ W2, const float* __restrict__ W3,
                     float* __restrict__ out, int K)
{
    int k = blockIdx.x * blockDim.x + threadIdx.x;
    if (k >= K) return;

    // ---- load per-element inputs ----
    float sv[18];
#pragma unroll
    for (int i = 0; i < 18; ++i) sv[i] = s[(size_t)k * 18 + i];
    float av[6];
#pragma unroll
    for (int i = 0; i < 6; ++i) av[i] = a[(size_t)k * 6 + i];
    float h0v[12];
#pragma unroll
    for (int i = 0; i < 12; ++i) h0v[i] = h0[(size_t)k * 12 + i];

    // x = concat(s[3:18], a[0:6])  (21)
    float x[21];
#pragma unroll
    for (int i = 0; i < 15; ++i) x[i] = sv[3 + i];
#pragma unroll
    for (int i = 0; i < 6; ++i) x[15 + i] = av[i];

    // ---- RNN cell: h1 = tanh(x @ W_ih^T + h0 @ W_hh^T) ----
    float h1[12];
#pragma unroll
    for (int j = 0; j < 12; ++j) {
        float acc = 0.0f;
#pragma unroll
        for (int i = 0; i < 21; ++i) acc = fmaf(W_ih[j * 21 + i], x[i], acc);
#pragma unroll
        for (int i = 0; i < 12; ++i) acc = fmaf(W_hh[j * 12 + i], h0v[i], acc);
        h1[j] = tanhf(acc);
    }

    // ---- MLP layer 1: l1 = lrelu(h1 @ W1^T)  (128) ----
    float l1[128];
#pragma unroll
    for (int j = 0; j < 128; ++j) {
        float acc = 0.0f;
#pragma unroll
        for (int i = 0; i < 12; ++i) acc = fmaf(W1[j * 12 + i], h1[i], acc);
        l1[j] = lrelu(acc);
    }

    // ---- MLP layers 2+3 fused: dv = lrelu(l1 @ W2^T) @ W3^T  (6) ----
    float dv[6] = {0.f, 0.f, 0.f, 0.f, 0.f, 0.f};
    for (int j = 0; j < 128; j += 4) {
        float a0 = 0.f, a1 = 0.f, a2 = 0.f, a3 = 0.f;
#pragma unroll
        for (int i = 0; i < 128; ++i) {
            const float li = l1[i];
            a0 = fmaf(W2[(j + 0) * 128 + i], li, a0);
            a1 = fmaf(W2[(j + 1) * 128 + i], li, a1);
            a2 = fmaf(W2[(j + 2) * 128 + i], li, a2);
            a3 = fmaf(W2[(j + 3) * 128 + i], li, a3);
        }
        a0 = lrelu(a0); a1 = lrelu(a1); a2 = lrelu(a2); a3 = lrelu(a3);
#pragma unroll
        for (int r = 0; r < 6; ++r) {
            dv[r] = fmaf(W3[r * 128 + (j + 0)], a0,
                    fmaf(W3[r * 128 + (j + 1)], a1,
                    fmaf(W3[r * 128 + (j + 2)], a2,
                    fmaf(W3[r * 128 + (j + 3)], a3, dv[r]))));
        }
    }

    // ---- SE(3) step (f32) ----
    const float* v = &sv[12];         // twist (6)
    const float* p = &sv[0];          // position (3)
    const float* R = &sv[3];          // rotation, row-major 3x3

    float rho[3] = {v[0] * DT_STEP, v[1] * DT_STEP, v[2] * DT_STEP};
    float phi[3] = {v[3] * DT_STEP, v[4] * DT_STEP, v[5] * DT_STEP};
    float th2 = phi[0] * phi[0] + phi[1] * phi[1] + phi[2] * phi[2];

    float A, B, C;
    if (th2 < 1e-8f) {
        A = 1.0f - th2 * (1.0f / 6.0f);
        B = 0.5f - th2 * (1.0f / 24.0f);
        C = (1.0f / 6.0f) - th2 * (1.0f / 120.0f);
    } else {
        float th = sqrtf(th2);
        float sn = sinf(th), cs = cosf(th);
        A = sn / th;
        B = (1.0f - cs) / th2;
        C = (th - sn) / (th2 * th);
    }

    float S[9] = {0.f, -phi[2], phi[1],
                  phi[2], 0.f, -phi[0],
                  -phi[1], phi[0], 0.f};
    float S2[9];
    mm3(S, S, S2);

    float Re[9], V[9];
#pragma unroll
    for (int i = 0; i < 9; ++i) {
        float I = (i == 0 || i == 4 || i == 8) ? 1.0f : 0.0f;
        Re[i] = I + A * S[i] + B * S2[i];
        V[i]  = I + B * S[i] + C * S2[i];
    }

    float pe[3];
    mv3(V, rho, pe);

    float Rn[9];
    mm3(R, Re, Rn);                      // R_next = R @ Re

    float pn[3];
    mv3(R, pe, pn);                      // p_next = R @ pe + p
    pn[0] += p[0]; pn[1] += p[1]; pn[2] += p[2];

    // Rinv = Rn^T ; pinv = -Rinv @ pn
    float pinv[3];
    mtv3(Rn, pn, pinv);
    pinv[0] = -pinv[0]; pinv[1] = -pinv[1]; pinv[2] = -pinv[2];

    // vI = adjoint(R, p) @ v
    float Rvl[3], Rva[3];
    mv3(R, &v[0], Rvl);                  // R @ v_lin
    mv3(R, &v[3], Rva);                  // R @ v_ang
    float px[3];
    cross3(p, Rva, px);                  // skew(p) @ (R @ v_ang)
    float u6[6];
    u6[0] = Rvl[0] + px[0] + dv[0];
    u6[1] = Rvl[1] + px[1] + dv[1];
    u6[2] = Rvl[2] + px[2] + dv[2];
    u6[3] = Rva[0] + dv[3];
    u6[4] = Rva[1] + dv[4];
    u6[5] = Rva[2] + dv[5];

    // v_next = adjoint(Rinv, pinv) @ u6
    float Rul[3], Rua[3];
    mtv3(Rn, &u6[0], Rul);               // Rinv @ u_lin
    mtv3(Rn, &u6[3], Rua);               // Rinv @ u_ang
    float pxu[3];
    cross3(pinv, Rua, pxu);
    float vn[6];
    vn[0] = Rul[0] + pxu[0];
    vn[1] = Rul[1] + pxu[1];
    vn[2] = Rul[2] + pxu[2];
    vn[3] = Rua[0];
    vn[4] = Rua[1];
    vn[5] = Rua[2];

    // ---- write outputs: s_next (K*18), hN (K*12), dv (K*6) ----
    float* s_next = out;
    float* hN     = out + (size_t)K * 18;
    float* dvo    = out + (size_t)K * 30;

    size_t ob = (size_t)k * 18;
    s_next[ob + 0] = pn[0]; s_next[ob + 1] = pn[1]; s_next[ob + 2] = pn[2];
#pragma unroll
    for (int i = 0; i < 9; ++i) s_next[ob + 3 + i] = Rn[i];
#pragma unroll
    for (int i = 0; i < 6; ++i) s_next[ob + 12 + i] = vn[i];

#pragma unroll
    for (int j = 0; j < 12; ++j) hN[(size_t)k * 12 + j] = h1[j];
#pragma unroll
    for (int r = 0; r < 6; ++r) dvo[(size_t)k * 6 + r] = dv[r];
}

extern "C" void kernel_launch(void* const* d_in, const int* in_sizes, int n_in,
                              void* d_out, int out_size, void* d_ws, size_t ws_size,
                              hipStream_t stream) {
    const float* s    = (const float*)d_in[0];
    const float* a    = (const float*)d_in[1];
    const float* h0   = (const float*)d_in[2];
    const float* W_ih = (const float*)d_in[3];
    const float* W_hh = (const float*)d_in[4];
    const float* W1   = (const float*)d_in[5];
    const float* W2   = (const float*)d_in[6];
    const float* W3   = (const float*)d_in[7];

    int K = in_sizes[0] / 18;
    int block = 256;
    int grid = (K + block - 1) / block;
    auv_step_kernel<<<grid, block, 0, stream>>>(s, a, h0, W_ih, W_hh, W1, W2, W3,
                                                (float*)d_out, K);
}

// Round 2
// 228.886 us; speedup vs baseline: 2.7463x; 2.7463x over previous
//
#include <hip/hip_runtime.h>
#include <math.h>

#define DT_STEP 0.1f

static __device__ __forceinline__ float lrelu(float z) { return z >= 0.0f ? z : 0.1f * z; }

static __device__ __forceinline__ void mm3(const float* A, const float* B, float* C) {
#pragma unroll
    for (int i = 0; i < 3; ++i) {
#pragma unroll
        for (int j = 0; j < 3; ++j) {
            C[i * 3 + j] = A[i * 3 + 0] * B[0 * 3 + j] + A[i * 3 + 1] * B[1 * 3 + j] + A[i * 3 + 2] * B[2 * 3 + j];
        }
    }
}

static __device__ __forceinline__ void mv3(const float* A, const float* x, float* y) {
#pragma unroll
    for (int i = 0; i < 3; ++i)
        y[i] = A[i * 3 + 0] * x[0] + A[i * 3 + 1] * x[1] + A[i * 3 + 2] * x[2];
}

// y = A^T x
static __device__ __forceinline__ void mtv3(const float* A, const float* x, float* y) {
#pragma unroll
    for (int i = 0; i < 3; ++i)
        y[i] = A[0 * 3 + i] * x[0] + A[1 * 3 + i] * x[1] + A[2 * 3 + i] * x[2];
}

static __device__ __forceinline__ void cross3(const float* p, const float* u, float* y) {
    y[0] = p[1] * u[2] - p[2] * u[1];
    y[1] = p[2] * u[0] - p[0] * u[2];
    y[2] = p[0] * u[1] - p[1] * u[0];
}

// 4 blocks/CU (=16 waves/CU = 4 waves/SIMD) -> caps VGPR at 128
__global__ __launch_bounds__(256, 4)
void auv_step_kernel(const float* __restrict__ s, const float* __restrict__ a,
                     const float* __restrict__ h0, const float* __restrict__ W_ih,
                     const float* __restrict__ W_hh, const float* __restrict__ W1,
                     const float* __restrict__ W2, const float* __restrict__ W3,
                     float* __restrict__ out, int K)
{
    int k = blockIdx.x * blockDim.x + threadIdx.x;
    if (k >= K) return;

    // ---- load per-element inputs ----
    float sv[18];
#pragma unroll
    for (int i = 0; i < 18; ++i) sv[i] = s[(size_t)k * 18 + i];
    float av[6];
#pragma unroll
    for (int i = 0; i < 6; ++i) av[i] = a[(size_t)k * 6 + i];

    // ---- RNN cell: h1 = tanh(x @ W_ih^T + h0 @ W_hh^T) ----
    // x = concat(s[3:18], a[0:6])  (21)
    float h1[12];
#pragma unroll
    for (int j = 0; j < 12; ++j) {
        float acc = 0.0f;
#pragma unroll
        for (int i = 0; i < 15; ++i) acc = fmaf(W_ih[j * 21 + i], sv[3 + i], acc);
#pragma unroll
        for (int i = 0; i < 6; ++i) acc = fmaf(W_ih[j * 21 + 15 + i], av[i], acc);
#pragma unroll
        for (int i = 0; i < 12; ++i) acc = fmaf(W_hh[j * 12 + i], h0[(size_t)k * 12 + i], acc);
        h1[j] = tanhf(acc);
    }

    // ---- MLP: dv = lrelu(lrelu(h1@W1^T)@W2^T)@W3^T ----
    // Tiled: 4 chunks of 32 layer-2 outputs; recompute l1 in slices of 16
    // to keep the register footprint ~<=128 VGPR (occupancy!).
    float dv[6] = {0.f, 0.f, 0.f, 0.f, 0.f, 0.f};
#pragma unroll 1
    for (int jc = 0; jc < 4; ++jc) {
        float l2acc[32];
#pragma unroll
        for (int j = 0; j < 32; ++j) l2acc[j] = 0.0f;

#pragma unroll 1
        for (int ic = 0; ic < 8; ++ic) {
            // l1 slice: l1c[t] = lrelu(sum_m W1[(ic*16+t)*12+m] * h1[m])
            float l1c[16];
#pragma unroll
            for (int t = 0; t < 16; ++t) {
                float acc = 0.0f;
                const float* w1r = &W1[(ic * 16 + t) * 12];
#pragma unroll
                for (int m = 0; m < 12; ++m) acc = fmaf(w1r[m], h1[m], acc);
                l1c[t] = lrelu(acc);
            }
            // accumulate into the 32 layer-2 outputs of this chunk
            const float* w2b = &W2[jc * 32 * 128 + ic * 16];
#pragma unroll
            for (int j = 0; j < 32; ++j) {
#pragma unroll
                for (int t = 0; t < 16; ++t) {
                    l2acc[j] = fmaf(w2b[j * 128 + t], l1c[t], l2acc[j]);
                }
            }
        }
        // lrelu + layer 3 accumulation
#pragma unroll
        for (int j = 0; j < 32; ++j) {
            float l2v = lrelu(l2acc[j]);
#pragma unroll
            for (int r = 0; r < 6; ++r) {
                dv[r] = fmaf(W3[r * 128 + jc * 32 + j], l2v, dv[r]);
            }
        }
    }

    // ---- SE(3) step (f32) ----
    const float* v = &sv[12];         // twist (6)
    const float* p = &sv[0];          // position (3)
    const float* R = &sv[3];          // rotation, row-major 3x3

    float rho[3] = {v[0] * DT_STEP, v[1] * DT_STEP, v[2] * DT_STEP};
    float phi[3] = {v[3] * DT_STEP, v[4] * DT_STEP, v[5] * DT_STEP};
    float th2 = phi[0] * phi[0] + phi[1] * phi[1] + phi[2] * phi[2];

    float A, B, C;
    if (th2 < 1e-8f) {
        A = 1.0f - th2 * (1.0f / 6.0f);
        B = 0.5f - th2 * (1.0f / 24.0f);
        C = (1.0f / 6.0f) - th2 * (1.0f / 120.0f);
    } else {
        float th = sqrtf(th2);
        float sn = sinf(th), cs = cosf(th);
        A = sn / th;
        B = (1.0f - cs) / th2;
        C = (th - sn) / (th2 * th);
    }

    float S[9] = {0.f, -phi[2], phi[1],
                  phi[2], 0.f, -phi[0],
                  -phi[1], phi[0], 0.f};
    float S2[9];
    mm3(S, S, S2);

    float Re[9], V[9];
#pragma unroll
    for (int i = 0; i < 9; ++i) {
        float I = (i == 0 || i == 4 || i == 8) ? 1.0f : 0.0f;
        Re[i] = I + A * S[i] + B * S2[i];
        V[i]  = I + B * S[i] + C * S2[i];
    }

    float pe[3];
    mv3(V, rho, pe);

    float Rn[9];
    mm3(R, Re, Rn);                      // R_next = R @ Re

    float pn[3];
    mv3(R, pe, pn);                      // p_next = R @ pe + p
    pn[0] += p[0]; pn[1] += p[1]; pn[2] += p[2];

    // Rinv = Rn^T ; pinv = -Rinv @ pn
    float pinv[3];
    mtv3(Rn, pn, pinv);
    pinv[0] = -pinv[0]; pinv[1] = -pinv[1]; pinv[2] = -pinv[2];

    // vI = adjoint(R, p) @ v
    float Rvl[3], Rva[3];
    mv3(R, &v[0], Rvl);                  // R @ v_lin
    mv3(R, &v[3], Rva);                  // R @ v_ang
    float px[3];
    cross3(p, Rva, px);                  // skew(p) @ (R @ v_ang)
    float u6[6];
    u6[0] = Rvl[0] + px[0] + dv[0];
    u6[1] = Rvl[1] + px[1] + dv[1];
    u6[2] = Rvl[2] + px[2] + dv[2];
    u6[3] = Rva[0] + dv[3];
    u6[4] = Rva[1] + dv[4];
    u6[5] = Rva[2] + dv[5];

    // v_next = adjoint(Rinv, pinv) @ u6
    float Rul[3], Rua[3];
    mtv3(Rn, &u6[0], Rul);               // Rinv @ u_lin
    mtv3(Rn, &u6[3], Rua);               // Rinv @ u_ang
    float pxu[3];
    cross3(pinv, Rua, pxu);
    float vn[6];
    vn[0] = Rul[0] + pxu[0];
    vn[1] = Rul[1] + pxu[1];
    vn[2] = Rul[2] + pxu[2];
    vn[3] = Rua[0];
    vn[4] = Rua[1];
    vn[5] = Rua[2];

    // ---- write outputs: s_next (K*18), hN (K*12), dv (K*6) ----
    float* s_next = out;
    float* hN     = out + (size_t)K * 18;
    float* dvo    = out + (size_t)K * 30;

    size_t ob = (size_t)k * 18;
    s_next[ob + 0] = pn[0]; s_next[ob + 1] = pn[1]; s_next[ob + 2] = pn[2];
#pragma unroll
    for (int i = 0; i < 9; ++i) s_next[ob + 3 + i] = Rn[i];
#pragma unroll
    for (int i = 0; i < 6; ++i) s_next[ob + 12 + i] = vn[i];

#pragma unroll
    for (int j = 0; j < 12; ++j) hN[(size_t)k * 12 + j] = h1[j];
#pragma unroll
    for (int r = 0; r < 6; ++r) dvo[(size_t)k * 6 + r] = dv[r];
}

extern "C" void kernel_launch(void* const* d_in, const int* in_sizes, int n_in,
                              void* d_out, int out_size, void* d_ws, size_t ws_size,
                              hipStream_t stream) {
    const float* s    = (const float*)d_in[0];
    const float* a    = (const float*)d_in[1];
    const float* h0   = (const float*)d_in[2];
    const float* W_ih = (const float*)d_in[3];
    const float* W_hh = (const float*)d_in[4];
    const float* W1   = (const float*)d_in[5];
    const float* W2   = (const float*)d_in[6];
    const float* W3   = (const float*)d_in[7];

    int K = in_sizes[0] / 18;
    int block = 256;
    int grid = (K + block - 1) / block;
    auv_step_kernel<<<grid, block, 0, stream>>>(s, a, h0, W_ih, W_hh, W1, W2, W3,
                                                (float*)d_out, K);
}

// Round 3
// 85.620 us; speedup vs baseline: 7.3416x; 2.6733x over previous
//
#include <hip/hip_runtime.h>
#include <math.h>

typedef __attribute__((ext_vector_type(8))) short short8;
typedef __attribute__((ext_vector_type(4))) float f32x4;

#define DT_STEP 0.1f

static __device__ __forceinline__ float lrelu(float z) { return fmaxf(z, 0.1f * z); }

static __device__ __forceinline__ unsigned bf16rne(float f) {
    unsigned u = __builtin_bit_cast(unsigned, f);
    return (u + 0x7fffu + ((u >> 16) & 1u)) >> 16;
}
static __device__ __forceinline__ float bf16tof(unsigned short h) {
    unsigned u = ((unsigned)h) << 16;
    return __builtin_bit_cast(float, u);
}
static __device__ __forceinline__ float tanh_fast(float v) {
    float e = __expf(2.0f * v);           // stable: large +v -> 1, large -v -> -1
    return 1.0f - 2.0f / (e + 1.0f);
}

static __device__ __forceinline__ void mm3(const float* A, const float* B, float* C) {
#pragma unroll
    for (int i = 0; i < 3; ++i)
#pragma unroll
        for (int j = 0; j < 3; ++j)
            C[i * 3 + j] = A[i * 3 + 0] * B[0 * 3 + j] + A[i * 3 + 1] * B[1 * 3 + j] + A[i * 3 + 2] * B[2 * 3 + j];
}
static __device__ __forceinline__ void mv3(const float* A, const float* x, float* y) {
#pragma unroll
    for (int i = 0; i < 3; ++i) y[i] = A[i * 3 + 0] * x[0] + A[i * 3 + 1] * x[1] + A[i * 3 + 2] * x[2];
}
static __device__ __forceinline__ void mtv3(const float* A, const float* x, float* y) {
#pragma unroll
    for (int i = 0; i < 3; ++i) y[i] = A[0 * 3 + i] * x[0] + A[1 * 3 + i] * x[1] + A[2 * 3 + i] * x[2];
}
static __device__ __forceinline__ void cross3(const float* p, const float* u, float* y) {
    y[0] = p[1] * u[2] - p[2] * u[1];
    y[1] = p[2] * u[0] - p[0] * u[2];
    y[2] = p[0] * u[1] - p[1] * u[0];
}

// W2 (128x128 f32) -> bf16 RNE into workspace
__global__ __launch_bounds__(256)
void w2_prep(const float* __restrict__ W2, unsigned short* __restrict__ o, int n) {
    int i = blockIdx.x * blockDim.x + threadIdx.x;
    if (i < n) o[i] = (unsigned short)bf16rne(W2[i]);
}

// Per-wave: 64 elements. Scalar RNN + l1 -> LDS(bf16, XOR-swizzled);
// layer2 via mfma_f32_16x16x32_bf16; l2 -> LDS; scalar layer3 + SE3.
// No __syncthreads: each wave uses only its own 16KB LDS slice.
__global__ __launch_bounds__(256, 2)
void auv_mfma_kernel(const float* __restrict__ s, const float* __restrict__ a,
                     const float* __restrict__ h0, const float* __restrict__ W_ih,
                     const float* __restrict__ W_hh, const float* __restrict__ W1,
                     const float* __restrict__ W3, const unsigned short* __restrict__ W2bf,
                     float* __restrict__ out, int K)
{
    __shared__ __align__(16) unsigned short lds[4][64 * 128];   // 64 KB total
    const int tid  = threadIdx.x;
    const int wid  = tid >> 6;
    const int lane = tid & 63;
    char* sbase = (char*)(&lds[wid][0]);                         // 16 KB per wave
    const int l15 = lane & 15;
    const int lg  = lane >> 4;
    const int swz = l15 << 4;                                    // (row&15)<<4 for row==lane (mod 16)

    const int e_raw = blockIdx.x * 256 + wid * 64 + lane;
    const int e  = e_raw < K ? e_raw : K - 1;                    // clamp loads; guard stores
    const bool live = e_raw < K;

    // ---------------- Phase A: RNN h1 + l1 -> LDS ----------------
    const float* srow = s  + (size_t)e * 18;
    const float* arow = a  + (size_t)e * 6;
    const float* hrow = h0 + (size_t)e * 12;

    float xv[21];
#pragma unroll
    for (int i = 0; i < 15; ++i) xv[i] = srow[3 + i];
#pragma unroll
    for (int i = 0; i < 6; ++i)  xv[15 + i] = arow[i];
    float h0v[12];
#pragma unroll
    for (int i = 0; i < 12; ++i) h0v[i] = hrow[i];

    float h1v[12];
#pragma unroll
    for (int j = 0; j < 12; ++j) {
        float acc = 0.f;
        const float* wih = W_ih + j * 21;
#pragma unroll
        for (int i = 0; i < 21; ++i) acc = fmaf(wih[i], xv[i], acc);
        const float* whh = W_hh + j * 12;
#pragma unroll
        for (int i = 0; i < 12; ++i) acc = fmaf(whh[i], h0v[i], acc);
        h1v[j] = tanh_fast(acc);
    }

    if (live) {   // hN output (f32, 16B-aligned)
        float4* h4 = (float4*)(out + (size_t)K * 18 + (size_t)e * 12);
        h4[0] = make_float4(h1v[0], h1v[1], h1v[2], h1v[3]);
        h4[1] = make_float4(h1v[4], h1v[5], h1v[6], h1v[7]);
        h4[2] = make_float4(h1v[8], h1v[9], h1v[10], h1v[11]);
    }

    // l1[k] = lrelu(W1[k,:] . h1), k wave-uniform -> W1 via s_load.
    // LDS layout: row = lane (element), 128 bf16 cols, byte = row*256 + (colbyte ^ ((row&15)<<4))
#pragma unroll
    for (int kb = 0; kb < 16; ++kb) {
        unsigned pk[4];
#pragma unroll
        for (int jp = 0; jp < 4; ++jp) {
            const float* w1r = W1 + (kb * 8 + jp * 2) * 12;
            float a0 = 0.f, a1 = 0.f;
#pragma unroll
            for (int m = 0; m < 12; ++m) {
                a0 = fmaf(w1r[m],      h1v[m], a0);
                a1 = fmaf(w1r[12 + m], h1v[m], a1);
            }
            a0 = lrelu(a0); a1 = lrelu(a1);
            pk[jp] = bf16rne(a0) | (bf16rne(a1) << 16);
        }
        *(uint4*)(sbase + lane * 256 + ((kb * 16) ^ swz)) = make_uint4(pk[0], pk[1], pk[2], pk[3]);
    }
    asm volatile("s_waitcnt lgkmcnt(0)" ::: "memory");
    __builtin_amdgcn_sched_barrier(0);

    // ---------------- A-fragments: lane holds l1[rt*16 + (lane&15)][kt*32 + (lane>>4)*8 + 0..7]
    short8 afr[4][4];
#pragma unroll
    for (int rt = 0; rt < 4; ++rt) {
#pragma unroll
        for (int kt = 0; kt < 4; ++kt) {
            int row  = rt * 16 + l15;
            int colb = kt * 64 + lg * 16;
            uint4 q = *(const uint4*)(sbase + row * 256 + (colb ^ swz));
            afr[rt][kt] = __builtin_bit_cast(short8, q);
        }
    }
    asm volatile("s_waitcnt lgkmcnt(0)" ::: "memory");   // reads done before l2 overwrites
    __builtin_amdgcn_sched_barrier(0);

    // ---------------- Layer 2 via MFMA; l2 (lrelu, bf16) back to same LDS slice
    // B-frag: lane holds W2[nt*16 + (lane&15)][kt*32 + (lane>>4)*8 + 0..7]  (= B[k][n], n=col)
    short8 bfr[4];
#pragma unroll
    for (int kt = 0; kt < 4; ++kt)
        bfr[kt] = __builtin_bit_cast(short8, *(const uint4*)(W2bf + (l15 * 128 + kt * 32 + lg * 8)));

#pragma unroll 1
    for (int nt = 0; nt < 8; ++nt) {
        short8 bnext[4];
        if (nt < 7) {
#pragma unroll
            for (int kt = 0; kt < 4; ++kt)
                bnext[kt] = __builtin_bit_cast(short8,
                    *(const uint4*)(W2bf + (((nt + 1) * 16 + l15) * 128 + kt * 32 + lg * 8)));
        }
        f32x4 acc[4];
#pragma unroll
        for (int rt = 0; rt < 4; ++rt) {
            acc[rt] = (f32x4){0.f, 0.f, 0.f, 0.f};
#pragma unroll
            for (int kt = 0; kt < 4; ++kt)
                acc[rt] = __builtin_amdgcn_mfma_f32_16x16x32_bf16(afr[rt][kt], bfr[kt], acc[rt], 0, 0, 0);
        }
        // C/D layout: col = lane&15 (neuron), row = rt*16 + (lane>>4)*4 + r  (element)
        const int colb2 = (nt * 16 + l15) * 2;
#pragma unroll
        for (int rt = 0; rt < 4; ++rt) {
#pragma unroll
            for (int r = 0; r < 4; ++r) {
                int row = rt * 16 + lg * 4 + r;
                float v = acc[rt][r];
                v = fmaxf(v, 0.1f * v);
                *(unsigned short*)(sbase + row * 256 + (colb2 ^ ((row & 15) << 4))) =
                    (unsigned short)bf16rne(v);
            }
        }
#pragma unroll
        for (int kt = 0; kt < 4; ++kt) bfr[kt] = bnext[kt];
    }
    asm volatile("s_waitcnt lgkmcnt(0)" ::: "memory");
    __builtin_amdgcn_sched_barrier(0);

    // ---------------- Layer 3: dv = l2(row=lane) @ W3^T   (W3 wave-uniform -> s_load)
    float dvv[6] = {0.f, 0.f, 0.f, 0.f, 0.f, 0.f};
#pragma unroll 1
    for (int cb = 0; cb < 16; ++cb) {
        uint4 q = *(const uint4*)(sbase + lane * 256 + ((cb * 16) ^ swz));
        unsigned u[4] = {q.x, q.y, q.z, q.w};
#pragma unroll
        for (int jp = 0; jp < 4; ++jp) {
            float v0 = bf16tof((unsigned short)(u[jp] & 0xffffu));
            float v1 = bf16tof((unsigned short)(u[jp] >> 16));
            int n = cb * 8 + jp * 2;
#pragma unroll
            for (int r = 0; r < 6; ++r) {
                dvv[r] = fmaf(W3[r * 128 + n],     v0, dvv[r]);
                dvv[r] = fmaf(W3[r * 128 + n + 1], v1, dvv[r]);
            }
        }
    }

    // ---------------- SE(3) step (f32) ----------------
    float sv[18];
#pragma unroll
    for (int i = 0; i < 18; ++i) sv[i] = srow[i];
    const float* v = &sv[12];
    const float* p = &sv[0];
    const float* R = &sv[3];

    float rho[3] = {v[0] * DT_STEP, v[1] * DT_STEP, v[2] * DT_STEP};
    float phi[3] = {v[3] * DT_STEP, v[4] * DT_STEP, v[5] * DT_STEP};
    float th2 = phi[0] * phi[0] + phi[1] * phi[1] + phi[2] * phi[2];

    float A, B, C;
    if (th2 < 1e-8f) {
        A = 1.0f - th2 * (1.0f / 6.0f);
        B = 0.5f - th2 * (1.0f / 24.0f);
        C = (1.0f / 6.0f) - th2 * (1.0f / 120.0f);
    } else {
        float th = sqrtf(th2);
        float sn = sinf(th), cs = cosf(th);
        A = sn / th;
        B = (1.0f - cs) / th2;
        C = (th - sn) / (th2 * th);
    }

    float S[9] = {0.f, -phi[2], phi[1], phi[2], 0.f, -phi[0], -phi[1], phi[0], 0.f};
    float S2[9];
    mm3(S, S, S2);

    float Re[9], V[9];
#pragma unroll
    for (int i = 0; i < 9; ++i) {
        float I = (i == 0 || i == 4 || i == 8) ? 1.0f : 0.0f;
        Re[i] = I + A * S[i] + B * S2[i];
        V[i]  = I + B * S[i] + C * S2[i];
    }

    float pe[3];
    mv3(V, rho, pe);
    float Rn[9];
    mm3(R, Re, Rn);
    float pn[3];
    mv3(R, pe, pn);
    pn[0] += p[0]; pn[1] += p[1]; pn[2] += p[2];

    float pinv[3];
    mtv3(Rn, pn, pinv);
    pinv[0] = -pinv[0]; pinv[1] = -pinv[1]; pinv[2] = -pinv[2];

    float Rvl[3], Rva[3];
    mv3(R, &v[0], Rvl);
    mv3(R, &v[3], Rva);
    float px[3];
    cross3(p, Rva, px);
    float u6[6];
    u6[0] = Rvl[0] + px[0] + dvv[0];
    u6[1] = Rvl[1] + px[1] + dvv[1];
    u6[2] = Rvl[2] + px[2] + dvv[2];
    u6[3] = Rva[0] + dvv[3];
    u6[4] = Rva[1] + dvv[4];
    u6[5] = Rva[2] + dvv[5];

    float Rul[3], Rua[3];
    mtv3(Rn, &u6[0], Rul);
    mtv3(Rn, &u6[3], Rua);
    float pxu[3];
    cross3(pinv, Rua, pxu);
    float vn[6];
    vn[0] = Rul[0] + pxu[0];
    vn[1] = Rul[1] + pxu[1];
    vn[2] = Rul[2] + pxu[2];
    vn[3] = Rua[0];
    vn[4] = Rua[1];
    vn[5] = Rua[2];

    if (live) {
        float* s_next = out + (size_t)e * 18;
        s_next[0] = pn[0]; s_next[1] = pn[1]; s_next[2] = pn[2];
#pragma unroll
        for (int i = 0; i < 9; ++i) s_next[3 + i] = Rn[i];
#pragma unroll
        for (int i = 0; i < 6; ++i) s_next[12 + i] = vn[i];

        float* dvo = out + (size_t)K * 30 + (size_t)e * 6;
#pragma unroll
        for (int r = 0; r < 6; ++r) dvo[r] = dvv[r];
    }
}

extern "C" void kernel_launch(void* const* d_in, const int* in_sizes, int n_in,
                              void* d_out, int out_size, void* d_ws, size_t ws_size,
                              hipStream_t stream) {
    const float* s    = (const float*)d_in[0];
    const float* a    = (const float*)d_in[1];
    const float* h0   = (const float*)d_in[2];
    const float* W_ih = (const float*)d_in[3];
    const float* W_hh = (const float*)d_in[4];
    const float* W1   = (const float*)d_in[5];
    const float* W2   = (const float*)d_in[6];
    const float* W3   = (const float*)d_in[7];

    int K = in_sizes[0] / 18;
    unsigned short* W2bf = (unsigned short*)d_ws;

    w2_prep<<<(16384 + 255) / 256, 256, 0, stream>>>(W2, W2bf, 16384);

    int grid = (K + 255) / 256;
    auv_mfma_kernel<<<grid, 256, 0, stream>>>(s, a, h0, W_ih, W_hh, W1, W3, W2bf,
                                              (float*)d_out, K);
}